// Round 10
// baseline (229.427 us; speedup 1.0000x reference)
//
#include <hip/hip_runtime.h>
#include <math.h>

#define NN 1024

typedef __attribute__((ext_vector_type(8))) short bf16x8;
typedef __attribute__((ext_vector_type(4))) float f32x4;
typedef __attribute__((ext_vector_type(2))) float f32x2;
typedef __attribute__((ext_vector_type(4))) unsigned int u32x4;

__device__ __forceinline__ float sigmoidf_(float x) { return 1.0f / (1.0f + __expf(-x)); }

// bf16 pair pack fallback, round-half-away: 3 VALU. lo = a, hi = b.
__device__ __forceinline__ unsigned int pk2(float a, float b) {
    return __builtin_amdgcn_perm(__float_as_uint(a) + 0x8000u,
                                 __float_as_uint(b) + 0x8000u, 0x03020706u);
}
// gfx950 single-instruction packed cvt when available (RNE)
__device__ __forceinline__ unsigned int pkcvt(float a, float b) {
#if __has_builtin(__builtin_amdgcn_cvt_pk_bf16_f32)
    return __builtin_bit_cast(unsigned int, __builtin_amdgcn_cvt_pk_bf16_f32(a, b));
#else
    return pk2(a, b);
#endif
}
__device__ __forceinline__ unsigned short f2bf_rne(float a) {
    unsigned int ua = __float_as_uint(a);
    ua += 0x7fffu + ((ua >> 16) & 1u);
    return (unsigned short)(ua >> 16);
}

// cfg layout (floats, per-lane SoA; each array 64 lanes x 4 dwords = 256):
//  +0 w2a0 | +256 w2a1 | +512 w3a0 | +768 w3a1
//  +1024 b2v0 | +1280 b2v1 | +1536 b3v0 | +1792 b3v1
//  +2048 wj lo | +2304 wj hi
#define CFG_FLOATS 2560

// ---------------------------------------------------------------------------
// k_pre: blocks 0..1023 transpose J -> Jt; 1024..1151 init h,u0,v;
//        block 1152 precomputes per-lane MFMA context into cfg.
// ---------------------------------------------------------------------------
__global__ __launch_bounds__(256) void k_pre(
    const float* __restrict__ J, const float* __restrict__ b,
    const float* __restrict__ W1, const float* __restrict__ b1,
    const float* __restrict__ W2, const float* __restrict__ b2,
    const float* __restrict__ W3, const float* __restrict__ b3,
    float* __restrict__ Jt, float* __restrict__ h,
    float* __restrict__ u0, float* __restrict__ v, float* __restrict__ cfg)
{
    __shared__ float tile[32][33];
    const int t = blockIdx.x;
    const int tid = threadIdx.x;
    if (t < 1024) {
        int tx = (t & 31) * 32, ty = (t >> 5) * 32;
        int x = tid & 31, y = tid >> 5;
#pragma unroll
        for (int r = 0; r < 4; r++)
            tile[y + 8 * r][x] = J[(size_t)(ty + y + 8 * r) * NN + tx + x];
        __syncthreads();
#pragma unroll
        for (int r = 0; r < 4; r++)
            Jt[(size_t)(tx + y + 8 * r) * NN + ty + x] = tile[x][y + 8 * r];
    } else if (t < 1152) {
        int idx = (t - 1024) * 256 + tid;
        int row = idx >> 5, mm = idx & 31;
        float bi = b[row];
        h[idx]  = 0.f;
        u0[idx] = bi * W1[mm * 67 + 65];
        v[idx]  = fmaf(bi, W1[mm * 67 + 66], b1[mm]);
    } else if (tid < 64) {
        const int l = tid, p = l & 15, q = l >> 4;
        union FU { unsigned int d[4]; unsigned short s[8]; } t0, t1, t2, t3;
        float wj[8];
#pragma unroll
        for (int jj = 0; jj < 8; jj++) {
            int k = q * 8 + jj;
            t0.s[jj] = f2bf_rne(W2[p * 32 + k]);
            t1.s[jj] = f2bf_rne(W2[(16 + p) * 32 + k]);
            t2.s[jj] = f2bf_rne(W3[p * 32 + k]);
            t3.s[jj] = f2bf_rne(W3[(16 + p) * 32 + k]);
            wj[jj] = W1[k * 67 + 64];
        }
        u32x4* cw = (u32x4*)cfg;
        cw[l]       = *(u32x4*)t0.d;
        cw[64 + l]  = *(u32x4*)t1.d;
        cw[128 + l] = *(u32x4*)t2.d;
        cw[192 + l] = *(u32x4*)t3.d;
        f32x4* cf = (f32x4*)(cfg + 1024);
        f32x4 v0, v1, v2, v3;
#pragma unroll
        for (int r = 0; r < 4; r++) {
            v0[r] = b2[q * 4 + r];  v1[r] = b2[16 + q * 4 + r];
            v2[r] = b3[q * 4 + r];  v3[r] = b3[16 + q * 4 + r];
        }
        cf[l] = v0; cf[64 + l] = v1; cf[128 + l] = v2; cf[192 + l] = v3;
        f32x4* cj = (f32x4*)(cfg + 2048);
        f32x4 wlo, whi;
#pragma unroll
        for (int r = 0; r < 4; r++) { wlo[r] = wj[r]; whi[r] = wj[4 + r]; }
        cj[l] = wlo; cj[64 + l] = whi;
    }
}

// ---------------------------------------------------------------------------
// one tile: X build (packed f32) -> MFMA W2 -> relu/cvt -> bpermute relayout
// -> MFMA W3 -> relu-acc (packed adds)
// ---------------------------------------------------------------------------
__device__ __forceinline__ void tile_body(
    float jw, const float4& ua_c, const float4& ub_c,
    const f32x2* vv2, const f32x2* wj2,
    const bf16x8& w2a0, const bf16x8& w2a1,
    const bf16x8& w3a0, const bf16x8& w3a1,
    const f32x4& b2v0, const f32x4& b2v1,
    const f32x4& b3v0, const f32x4& b3v1,
    int s0, int s1, bool qlo, f32x4& acc0, f32x4& acc1)
{
    const f32x2 jw2 = {jw, jw};
    const f32x2 z2 = {0.f, 0.f};
    const f32x4 z4 = {0.f, 0.f, 0.f, 0.f};

    f32x2 x0 = {ua_c.x, ua_c.y}, x1 = {ua_c.z, ua_c.w};
    f32x2 x2 = {ub_c.x, ub_c.y}, x3 = {ub_c.z, ub_c.w};
    x0 = jw2 * wj2[0] + (x0 + vv2[0]);   // v_pk_fma / v_pk_add
    x1 = jw2 * wj2[1] + (x1 + vv2[1]);
    x2 = jw2 * wj2[2] + (x2 + vv2[2]);
    x3 = jw2 * wj2[3] + (x3 + vv2[3]);
    x0 = __builtin_elementwise_max(x0, z2);
    x1 = __builtin_elementwise_max(x1, z2);
    x2 = __builtin_elementwise_max(x2, z2);
    x3 = __builtin_elementwise_max(x3, z2);

    union BU { u32x4 u4; bf16x8 v; unsigned int d[4]; } bx;
    bx.d[0] = pkcvt(x0[0], x0[1]);
    bx.d[1] = pkcvt(x1[0], x1[1]);
    bx.d[2] = pkcvt(x2[0], x2[1]);
    bx.d[3] = pkcvt(x3[0], x3[1]);

    f32x4 c0 = __builtin_amdgcn_mfma_f32_16x16x32_bf16(w2a0, bx.v, b2v0, 0, 0, 0);
    f32x4 c1 = __builtin_amdgcn_mfma_f32_16x16x32_bf16(w2a1, bx.v, b2v1, 0, 0, 0);
    c0 = __builtin_elementwise_max(c0, z4);
    c1 = __builtin_elementwise_max(c1, z4);

    const int d0 = (int)pkcvt(c0[0], c0[1]);
    const int d1 = (int)pkcvt(c0[2], c0[3]);
    const int d2 = (int)pkcvt(c1[0], c1[1]);
    const int d3 = (int)pkcvt(c1[2], c1[3]);

    const int A0 = __builtin_amdgcn_ds_bpermute(s0, d0);
    const int A1 = __builtin_amdgcn_ds_bpermute(s0, d1);
    const int A2 = __builtin_amdgcn_ds_bpermute(s1, d0);
    const int A3 = __builtin_amdgcn_ds_bpermute(s1, d1);
    const int B0 = __builtin_amdgcn_ds_bpermute(s0, d2);
    const int B1 = __builtin_amdgcn_ds_bpermute(s0, d3);
    const int B2 = __builtin_amdgcn_ds_bpermute(s1, d2);
    const int B3 = __builtin_amdgcn_ds_bpermute(s1, d3);

    union BU yr;
    yr.d[0] = (unsigned)(qlo ? A0 : B0);
    yr.d[1] = (unsigned)(qlo ? A1 : B1);
    yr.d[2] = (unsigned)(qlo ? A2 : B2);
    yr.d[3] = (unsigned)(qlo ? A3 : B3);

    f32x4 e0 = __builtin_amdgcn_mfma_f32_16x16x32_bf16(w3a0, yr.v, b3v0, 0, 0, 0);
    f32x4 e1 = __builtin_amdgcn_mfma_f32_16x16x32_bf16(w3a1, yr.v, b3v1, 0, 0, 0);
    acc0 = acc0 + __builtin_elementwise_max(e0, z4);   // v_pk_add_f32 x2
    acc1 = acc1 + __builtin_elementwise_max(e1, z4);
}

// ---------------------------------------------------------------------------
// k_main: 2048 blocks x 256 (2 blocks per j, 512 i's each; 4 waves x 8 tiles).
// Writes partial 32-vec sums to mpart[half][j][32]. No tail -> no 192-thread
// serialization; grid 2048 lets >4 blocks/CU co-reside (VGPR-limited ~5).
// ---------------------------------------------------------------------------
__global__ __launch_bounds__(256, 4) void k_main(
    const float* __restrict__ Jt, const float* __restrict__ cfg,
    const float* __restrict__ v, const float* __restrict__ ui,
    float* __restrict__ mpart)
{
    __shared__ float red[4 * 32];
    const int tid = threadIdx.x;
    const int w = tid >> 6;
    const int l = tid & 63;
    const int p = l & 15;
    const int q = l >> 4;
    const int j = blockIdx.x >> 1;
    const int half = blockIdx.x & 1;

    union FU { bf16x8 v; u32x4 u4; } w2a0, w2a1, w3a0, w3a1;
    const u32x4* cw = (const u32x4*)cfg;
    w2a0.u4 = cw[l]; w2a1.u4 = cw[64 + l]; w3a0.u4 = cw[128 + l]; w3a1.u4 = cw[192 + l];
    const f32x4* cf = (const f32x4*)(cfg + 1024);
    const f32x4 b2v0 = cf[l], b2v1 = cf[64 + l], b3v0 = cf[128 + l], b3v1 = cf[192 + l];
    const f32x4* cj = (const f32x4*)(cfg + 2048);
    const f32x4 wlo = cj[l], whi = cj[64 + l];
    f32x2 wj2[4] = { {wlo[0], wlo[1]}, {wlo[2], wlo[3]}, {whi[0], whi[1]}, {whi[2], whi[3]} };

    f32x2 vv2[4];
    {
        float4 va = *(const float4*)(v + j * 32 + q * 8);
        float4 vb = *(const float4*)(v + j * 32 + q * 8 + 4);
        vv2[0] = f32x2{va.x, va.y}; vv2[1] = f32x2{va.z, va.w};
        vv2[2] = f32x2{vb.x, vb.y}; vv2[3] = f32x2{vb.z, vb.w};
    }

    const float* Jtrow = Jt + (size_t)j * NN;
    const int s0 = (p | ((l & 16) << 1)) << 2;
    const int s1 = s0 + 64;
    const bool qlo = (l & 32) == 0;

    f32x4 acc0 = {0.f, 0.f, 0.f, 0.f}, acc1 = {0.f, 0.f, 0.f, 0.f};

    // 8 tiles per wave, processed in pairs with explicit even/odd regs
    const int ibase = half * 512 + w * 128;
    int iA = ibase + p, iB = ibase + 16 + p;
    float  jwA = Jtrow[iA];
    float4 uaA = *(const float4*)(ui + iA * 32 + q * 8);
    float4 ubA = *(const float4*)(ui + iA * 32 + q * 8 + 4);
    float  jwB = Jtrow[iB];
    float4 uaB = *(const float4*)(ui + iB * 32 + q * 8);
    float4 ubB = *(const float4*)(ui + iB * 32 + q * 8 + 4);

#pragma unroll
    for (int tt = 0; tt < 4; ++tt) {
        const float  jwA_c = jwA; const float4 uaA_c = uaA, ubA_c = ubA;
        const float  jwB_c = jwB; const float4 uaB_c = uaB, ubB_c = ubB;
        if (tt < 3) {
            const int inA = ibase + (2 * tt + 2) * 16 + p;
            const int inB = inA + 16;
            jwA = Jtrow[inA];
            uaA = *(const float4*)(ui + inA * 32 + q * 8);
            ubA = *(const float4*)(ui + inA * 32 + q * 8 + 4);
            jwB = Jtrow[inB];
            uaB = *(const float4*)(ui + inB * 32 + q * 8);
            ubB = *(const float4*)(ui + inB * 32 + q * 8 + 4);
        }
        tile_body(jwA_c, uaA_c, ubA_c, vv2, wj2, w2a0.v, w2a1.v, w3a0.v, w3a1.v,
                  b2v0, b2v1, b3v0, b3v1, s0, s1, qlo, acc0, acc1);
        tile_body(jwB_c, uaB_c, ubB_c, vv2, wj2, w2a0.v, w2a1.v, w3a0.v, w3a1.v,
                  b2v0, b2v1, b3v0, b3v1, s0, s1, qlo, acc0, acc1);
    }

    // reduce over p (lane bits 0..3), then waves via LDS
#pragma unroll
    for (int bit = 1; bit < 16; bit <<= 1) {
#pragma unroll
        for (int r = 0; r < 4; r++) {
            acc0[r] += __shfl_xor(acc0[r], bit);
            acc1[r] += __shfl_xor(acc1[r], bit);
        }
    }
    if (p == 0) {
#pragma unroll
        for (int r = 0; r < 4; r++) {
            red[w * 32 + q * 4 + r]      = acc0[r];
            red[w * 32 + 16 + q * 4 + r] = acc1[r];
        }
    }
    __syncthreads();
    if (tid < 32)
        mpart[(half << 15) + j * 32 + tid] =
            red[tid] + red[32 + tid] + red[64 + tid] + red[96 + tid];
}

// ---------------------------------------------------------------------------
// k_tail: GRU + u/v refresh (+ readout). One block per j, all phases wide.
// ---------------------------------------------------------------------------
__global__ __launch_bounds__(256) void k_tail(
    const float* __restrict__ Wih, const float* __restrict__ bih,
    const float* __restrict__ bhh, const float* __restrict__ b,
    const float* __restrict__ b1, const float* __restrict__ W1,
    const float* __restrict__ R1, const float* __restrict__ rb1,
    const float* __restrict__ R2, const float* __restrict__ rb2,
    const float* __restrict__ R3, const float* __restrict__ rb3,
    float* __restrict__ h, float* __restrict__ v,
    const float* __restrict__ mpart, float* __restrict__ uo,
    float* __restrict__ out, int do_out)
{
    __shared__ float hm[64], gbuf[96], hnb[32], tb[32];
    const int tid = threadIdx.x;
    const int j = blockIdx.x;

    if (tid < 64) {
        float val;
        if (tid < 32) val = h[j * 32 + tid];
        else {
            int s = tid - 32;
            val = mpart[j * 32 + s] + mpart[32768 + j * 32 + s];
        }
        hm[tid] = val;
    }
    __syncthreads();

    if (tid < 192) {
        const int row = tid >> 1, half = tid & 1;
        const float* wr = Wih + row * 64 + half * 32;
        const float* hh = hm + half * 32;
        float acc = 0.f;
#pragma unroll
        for (int k4 = 0; k4 < 8; k4++) {
            float4 w4 = *(const float4*)(wr + 4 * k4);
            acc = fmaf(w4.x, hh[4 * k4 + 0], acc);
            acc = fmaf(w4.y, hh[4 * k4 + 1], acc);
            acc = fmaf(w4.z, hh[4 * k4 + 2], acc);
            acc = fmaf(w4.w, hh[4 * k4 + 3], acc);
        }
        acc += __shfl_xor(acc, 1);
        if (half == 0) gbuf[row] = acc + bih[row];
    }
    __syncthreads();

    if (tid < 32) {
        const int s = tid;
        float r = sigmoidf_(gbuf[s] + bhh[s]);
        float z = sigmoidf_(gbuf[32 + s] + bhh[32 + s]);
        float n = tanhf(gbuf[64 + s] + r * bhh[64 + s]);
        float hn_ = (1.0f - z) * n;
        hnb[s] = hn_;
        h[j * 32 + s] = hn_;
    }
    __syncthreads();

    if (tid < 64) {
        const int s = tid & 31;
        const bool isV = tid >= 32;
        const float bj = b[j];
        const float* wr = W1 + s * 67 + (isV ? 32 : 0);
        float acc = isV ? fmaf(bj, W1[s * 67 + 66], b1[s]) : bj * W1[s * 67 + 65];
#pragma unroll
        for (int k = 0; k < 32; k++) acc = fmaf(wr[k], hnb[k], acc);
        if (isV) v[j * 32 + s] = acc;
        else     uo[j * 32 + s] = acc;
    }

    if (do_out) {
        __syncthreads();
        if (tid < 32) {
            float a = rb1[tid];
            const float* rr = R1 + tid * 32;
#pragma unroll 8
            for (int k = 0; k < 32; k++) a = fmaf(rr[k], hnb[k], a);
            gbuf[tid] = fmaxf(a, 0.f);
        }
        __syncthreads();
        if (tid < 32) {
            float a = rb2[tid];
            const float* rr = R2 + tid * 32;
#pragma unroll 8
            for (int k = 0; k < 32; k++) a = fmaf(rr[k], gbuf[k], a);
            tb[tid] = fmaxf(a, 0.f);
        }
        __syncthreads();
        if (tid < 2) {
            float a = rb3[tid];
            const float* rr = R3 + tid * 32;
#pragma unroll 8
            for (int k = 0; k < 32; k++) a = fmaf(rr[k], tb[k], a);
            out[j * 2 + tid] = sigmoidf_(fmaxf(a, 0.f));
        }
    }
}

// ---------------------------------------------------------------------------
extern "C" void kernel_launch(void* const* d_in, const int* in_sizes, int n_in,
                              void* d_out, int out_size, void* d_ws, size_t ws_size,
                              hipStream_t stream)
{
    const float* J   = (const float*)d_in[0];
    const float* b   = (const float*)d_in[1];
    const float* W1  = (const float*)d_in[2];
    const float* b1  = (const float*)d_in[3];
    const float* W2  = (const float*)d_in[4];
    const float* b2  = (const float*)d_in[5];
    const float* W3  = (const float*)d_in[6];
    const float* b3  = (const float*)d_in[7];
    const float* Wih = (const float*)d_in[8];
    const float* bih = (const float*)d_in[9];
    const float* bhh = (const float*)d_in[10];
    const float* R1  = (const float*)d_in[11];
    const float* rb1 = (const float*)d_in[12];
    const float* R2  = (const float*)d_in[13];
    const float* rb2 = (const float*)d_in[14];
    const float* R3  = (const float*)d_in[15];
    const float* rb3 = (const float*)d_in[16];

    float* out = (float*)d_out;
    float* ws  = (float*)d_ws;
    float* h     = ws;
    float* v     = ws + 32768;
    float* u0    = ws + 65536;
    float* u1    = ws + 98304;
    float* Jt    = ws + 131072;
    float* cfg   = ws + 131072 + NN * NN;
    float* mpart = cfg + CFG_FLOATS;

    k_pre<<<1153, 256, 0, stream>>>(J, b, W1, b1, W2, b2, W3, b3,
                                    Jt, h, u0, v, cfg);
    for (int s = 0; s < 5; s++) {
        const float* ui = (s & 1) ? u1 : u0;
        float*       uo = (s & 1) ? u0 : u1;
        k_main<<<2048, 256, 0, stream>>>(Jt, cfg, v, ui, mpart);
        k_tail<<<1024, 256, 0, stream>>>(Wih, bih, bhh, b, b1, W1,
                                         R1, rb1, R2, rb2, R3, rb3,
                                         h, v, mpart, uo, out, (s == 4) ? 1 : 0);
    }
}

// Round 11
// 201.985 us; speedup vs baseline: 1.1359x; 1.1359x over previous
//
#include <hip/hip_runtime.h>
#include <math.h>

#define NN 1024

typedef __attribute__((ext_vector_type(8))) short bf16x8;
typedef __attribute__((ext_vector_type(4))) float f32x4;
typedef __attribute__((ext_vector_type(2))) float f32x2;
typedef __attribute__((ext_vector_type(4))) unsigned int u32x4;

__device__ __forceinline__ float sigmoidf_(float x) { return 1.0f / (1.0f + __expf(-x)); }

// bf16 pair pack fallback, round-half-away: 3 VALU. lo = a, hi = b.
__device__ __forceinline__ unsigned int pk2(float a, float b) {
    return __builtin_amdgcn_perm(__float_as_uint(a) + 0x8000u,
                                 __float_as_uint(b) + 0x8000u, 0x03020706u);
}
// gfx950 single-instruction packed cvt when available (RNE)
__device__ __forceinline__ unsigned int pkcvt(float a, float b) {
#if __has_builtin(__builtin_amdgcn_cvt_pk_bf16_f32)
    return __builtin_bit_cast(unsigned int, __builtin_amdgcn_cvt_pk_bf16_f32(a, b));
#else
    return pk2(a, b);
#endif
}
__device__ __forceinline__ unsigned short f2bf_rne(float a) {
    unsigned int ua = __float_as_uint(a);
    ua += 0x7fffu + ((ua >> 16) & 1u);
    return (unsigned short)(ua >> 16);
}

// cfg layout (floats, per-lane SoA; each array 64 lanes x 4 dwords = 256):
//  +0 w2a0 | +256 w2a1 | +512 w3a0 | +768 w3a1
//  +1024 b2v0 | +1280 b2v1 | +1536 b3v0 | +1792 b3v1
//  +2048 wj lo | +2304 wj hi
#define CFG_FLOATS 2560

// ---------------------------------------------------------------------------
// k_pre: blocks 0..1023 transpose J -> Jt; 1024..1151 init h,u0,v;
//        block 1152 precomputes per-lane MFMA context into cfg.
// ---------------------------------------------------------------------------
__global__ __launch_bounds__(256) void k_pre(
    const float* __restrict__ J, const float* __restrict__ b,
    const float* __restrict__ W1, const float* __restrict__ b1,
    const float* __restrict__ W2, const float* __restrict__ b2,
    const float* __restrict__ W3, const float* __restrict__ b3,
    float* __restrict__ Jt, float* __restrict__ h,
    float* __restrict__ u0, float* __restrict__ v, float* __restrict__ cfg)
{
    __shared__ float tile[32][33];
    const int t = blockIdx.x;
    const int tid = threadIdx.x;
    if (t < 1024) {
        int tx = (t & 31) * 32, ty = (t >> 5) * 32;
        int x = tid & 31, y = tid >> 5;
#pragma unroll
        for (int r = 0; r < 4; r++)
            tile[y + 8 * r][x] = J[(size_t)(ty + y + 8 * r) * NN + tx + x];
        __syncthreads();
#pragma unroll
        for (int r = 0; r < 4; r++)
            Jt[(size_t)(tx + y + 8 * r) * NN + ty + x] = tile[x][y + 8 * r];
    } else if (t < 1152) {
        int idx = (t - 1024) * 256 + tid;
        int row = idx >> 5, mm = idx & 31;
        float bi = b[row];
        h[idx]  = 0.f;
        u0[idx] = bi * W1[mm * 67 + 65];
        v[idx]  = fmaf(bi, W1[mm * 67 + 66], b1[mm]);
    } else if (tid < 64) {
        const int l = tid, p = l & 15, q = l >> 4;
        union FU { unsigned int d[4]; unsigned short s[8]; } t0, t1, t2, t3;
        float wj[8];
#pragma unroll
        for (int jj = 0; jj < 8; jj++) {
            int k = q * 8 + jj;
            t0.s[jj] = f2bf_rne(W2[p * 32 + k]);
            t1.s[jj] = f2bf_rne(W2[(16 + p) * 32 + k]);
            t2.s[jj] = f2bf_rne(W3[p * 32 + k]);
            t3.s[jj] = f2bf_rne(W3[(16 + p) * 32 + k]);
            wj[jj] = W1[k * 67 + 64];
        }
        u32x4* cw = (u32x4*)cfg;
        cw[l]       = *(u32x4*)t0.d;
        cw[64 + l]  = *(u32x4*)t1.d;
        cw[128 + l] = *(u32x4*)t2.d;
        cw[192 + l] = *(u32x4*)t3.d;
        f32x4* cf = (f32x4*)(cfg + 1024);
        f32x4 v0, v1, v2, v3;
#pragma unroll
        for (int r = 0; r < 4; r++) {
            v0[r] = b2[q * 4 + r];  v1[r] = b2[16 + q * 4 + r];
            v2[r] = b3[q * 4 + r];  v3[r] = b3[16 + q * 4 + r];
        }
        cf[l] = v0; cf[64 + l] = v1; cf[128 + l] = v2; cf[192 + l] = v3;
        f32x4* cj = (f32x4*)(cfg + 2048);
        f32x4 wlo, whi;
#pragma unroll
        for (int r = 0; r < 4; r++) { wlo[r] = wj[r]; whi[r] = wj[4 + r]; }
        cj[l] = wlo; cj[64 + l] = whi;
    }
}

// ---------------------------------------------------------------------------
// one tile: X build (packed f32) -> MFMA W2 -> relu/cvt -> bpermute relayout
// -> MFMA W3 -> relu-acc (packed adds)
// ---------------------------------------------------------------------------
__device__ __forceinline__ void tile_body(
    float jw, const float4& ua_c, const float4& ub_c,
    const f32x2* vv2, const f32x2* wj2,
    const bf16x8& w2a0, const bf16x8& w2a1,
    const bf16x8& w3a0, const bf16x8& w3a1,
    const f32x4& b2v0, const f32x4& b2v1,
    const f32x4& b3v0, const f32x4& b3v1,
    int s0, int s1, bool qlo, f32x4& acc0, f32x4& acc1)
{
    const f32x2 jw2 = {jw, jw};
    const f32x2 z2 = {0.f, 0.f};
    const f32x4 z4 = {0.f, 0.f, 0.f, 0.f};

    f32x2 x0 = {ua_c.x, ua_c.y}, x1 = {ua_c.z, ua_c.w};
    f32x2 x2 = {ub_c.x, ub_c.y}, x3 = {ub_c.z, ub_c.w};
    x0 = jw2 * wj2[0] + (x0 + vv2[0]);   // v_pk_fma / v_pk_add
    x1 = jw2 * wj2[1] + (x1 + vv2[1]);
    x2 = jw2 * wj2[2] + (x2 + vv2[2]);
    x3 = jw2 * wj2[3] + (x3 + vv2[3]);
    x0 = __builtin_elementwise_max(x0, z2);
    x1 = __builtin_elementwise_max(x1, z2);
    x2 = __builtin_elementwise_max(x2, z2);
    x3 = __builtin_elementwise_max(x3, z2);

    union BU { u32x4 u4; bf16x8 v; unsigned int d[4]; } bx;
    bx.d[0] = pkcvt(x0[0], x0[1]);
    bx.d[1] = pkcvt(x1[0], x1[1]);
    bx.d[2] = pkcvt(x2[0], x2[1]);
    bx.d[3] = pkcvt(x3[0], x3[1]);

    f32x4 c0 = __builtin_amdgcn_mfma_f32_16x16x32_bf16(w2a0, bx.v, b2v0, 0, 0, 0);
    f32x4 c1 = __builtin_amdgcn_mfma_f32_16x16x32_bf16(w2a1, bx.v, b2v1, 0, 0, 0);
    c0 = __builtin_elementwise_max(c0, z4);
    c1 = __builtin_elementwise_max(c1, z4);

    const int d0 = (int)pkcvt(c0[0], c0[1]);
    const int d1 = (int)pkcvt(c0[2], c0[3]);
    const int d2 = (int)pkcvt(c1[0], c1[1]);
    const int d3 = (int)pkcvt(c1[2], c1[3]);

    const int A0 = __builtin_amdgcn_ds_bpermute(s0, d0);
    const int A1 = __builtin_amdgcn_ds_bpermute(s0, d1);
    const int A2 = __builtin_amdgcn_ds_bpermute(s1, d0);
    const int A3 = __builtin_amdgcn_ds_bpermute(s1, d1);
    const int B0 = __builtin_amdgcn_ds_bpermute(s0, d2);
    const int B1 = __builtin_amdgcn_ds_bpermute(s0, d3);
    const int B2 = __builtin_amdgcn_ds_bpermute(s1, d2);
    const int B3 = __builtin_amdgcn_ds_bpermute(s1, d3);

    union BU yr;
    yr.d[0] = (unsigned)(qlo ? A0 : B0);
    yr.d[1] = (unsigned)(qlo ? A1 : B1);
    yr.d[2] = (unsigned)(qlo ? A2 : B2);
    yr.d[3] = (unsigned)(qlo ? A3 : B3);

    f32x4 e0 = __builtin_amdgcn_mfma_f32_16x16x32_bf16(w3a0, yr.v, b3v0, 0, 0, 0);
    f32x4 e1 = __builtin_amdgcn_mfma_f32_16x16x32_bf16(w3a1, yr.v, b3v1, 0, 0, 0);
    acc0 = acc0 + __builtin_elementwise_max(e0, z4);
    acc1 = acc1 + __builtin_elementwise_max(e1, z4);
}

// ---------------------------------------------------------------------------
// k_step: one recurrence step, tail fused (6 launches total / run).
// 1024 blocks x 256 threads, 4 waves x 16 tiles (8 pairs).
// Address scheme: loop-invariant base pointers; all tile loads use
// compile-time immediate offsets (J stride 64B: one addr reg for all 16
// tiles; u stride 2048B: one addr reg per pair, advanced by a single
// 64-bit add) -- kills the per-load 64-bit address arithmetic.
// ---------------------------------------------------------------------------
__global__ __launch_bounds__(256, 4) void k_step(
    const float* __restrict__ Jt, const float* __restrict__ cfg,
    const float* __restrict__ Wih, const float* __restrict__ bih,
    const float* __restrict__ bhh, const float* __restrict__ b,
    const float* __restrict__ b1, const float* __restrict__ W1,
    const float* __restrict__ R1, const float* __restrict__ rb1,
    const float* __restrict__ R2, const float* __restrict__ rb2,
    const float* __restrict__ R3, const float* __restrict__ rb3,
    float* __restrict__ h, float* __restrict__ v,
    const float* __restrict__ ui, float* __restrict__ uo,
    float* __restrict__ out, int do_out)
{
    __shared__ float red[4 * 32];
    __shared__ float hm[64], gbuf[96], hnb[32], tb[32];

    const int tid = threadIdx.x;
    const int w = tid >> 6;
    const int l = tid & 63;
    const int p = l & 15;
    const int q = l >> 4;
    const int j = blockIdx.x;

    // ---- coalesced per-lane context (10 x 16B) ----
    union FU { bf16x8 v; u32x4 u4; } w2a0, w2a1, w3a0, w3a1;
    const u32x4* cw = (const u32x4*)cfg;
    w2a0.u4 = cw[l]; w2a1.u4 = cw[64 + l]; w3a0.u4 = cw[128 + l]; w3a1.u4 = cw[192 + l];
    const f32x4* cf = (const f32x4*)(cfg + 1024);
    const f32x4 b2v0 = cf[l], b2v1 = cf[64 + l], b3v0 = cf[128 + l], b3v1 = cf[192 + l];
    const f32x4* cj = (const f32x4*)(cfg + 2048);
    const f32x4 wlo = cj[l], whi = cj[64 + l];
    f32x2 wj2[4] = { {wlo[0], wlo[1]}, {wlo[2], wlo[3]}, {whi[0], whi[1]}, {whi[2], whi[3]} };

    f32x2 vv2[4];
    {
        float4 va = *(const float4*)(v + j * 32 + q * 8);
        float4 vb = *(const float4*)(v + j * 32 + q * 8 + 4);
        vv2[0] = f32x2{va.x, va.y}; vv2[1] = f32x2{va.z, va.w};
        vv2[2] = f32x2{vb.x, vb.y}; vv2[3] = f32x2{vb.z, vb.w};
    }

    const int s0 = (p | ((l & 16) << 1)) << 2;
    const int s1 = s0 + 64;
    const bool qlo = (l & 32) == 0;

    f32x4 acc0 = {0.f, 0.f, 0.f, 0.f}, acc1 = {0.f, 0.f, 0.f, 0.f};

    // ---- base pointers (loop-invariant; imm-offset loads) ----
    const int ibase = w * 256;
    const float* jp = Jt + (size_t)j * NN + ibase + p;          // tile t: +t*16 floats
    const float* up = ui + (size_t)(ibase + p) * 32 + q * 8;    // pair tt: +tt*1024 floats

    // prefetch pair 0
    float  jwA = jp[0],  jwB = jp[16];
    float4 uaA = *(const float4*)(up);
    float4 ubA = *(const float4*)(up + 4);
    float4 uaB = *(const float4*)(up + 512);
    float4 ubB = *(const float4*)(up + 516);

#pragma unroll
    for (int tt = 0; tt < 8; ++tt) {
        const float  jwA_c = jwA; const float4 uaA_c = uaA, ubA_c = ubA;
        const float  jwB_c = jwB; const float4 uaB_c = uaB, ubB_c = ubB;
        if (tt < 7) {
            const float* jn = jp + (tt + 1) * 32;
            const float* un = up + (size_t)(tt + 1) * 1024;
            jwA = jn[0];  jwB = jn[16];
            uaA = *(const float4*)(un);
            ubA = *(const float4*)(un + 4);
            uaB = *(const float4*)(un + 512);
            ubB = *(const float4*)(un + 516);
        }
        tile_body(jwA_c, uaA_c, ubA_c, vv2, wj2, w2a0.v, w2a1.v, w3a0.v, w3a1.v,
                  b2v0, b2v1, b3v0, b3v1, s0, s1, qlo, acc0, acc1);
        tile_body(jwB_c, uaB_c, ubB_c, vv2, wj2, w2a0.v, w2a1.v, w3a0.v, w3a1.v,
                  b2v0, b2v1, b3v0, b3v1, s0, s1, qlo, acc0, acc1);
    }

    // reduce over p (lane bits 0..3), then waves via LDS
#pragma unroll
    for (int bit = 1; bit < 16; bit <<= 1) {
#pragma unroll
        for (int r = 0; r < 4; r++) {
            acc0[r] += __shfl_xor(acc0[r], bit);
            acc1[r] += __shfl_xor(acc1[r], bit);
        }
    }
    if (p == 0) {
#pragma unroll
        for (int r = 0; r < 4; r++) {
            red[w * 32 + q * 4 + r]      = acc0[r];
            red[w * 32 + 16 + q * 4 + r] = acc1[r];
        }
    }
    __syncthreads();

    // ---- tail: GRU + u/v refresh (+ readout) ----
    if (tid < 64) {
        float val;
        if (tid < 32) val = h[j * 32 + tid];
        else {
            int s = tid - 32;
            val = red[s] + red[32 + s] + red[64 + s] + red[96 + s];
        }
        hm[tid] = val;
    }
    __syncthreads();

    if (tid < 192) {
        const int row = tid >> 1, half = tid & 1;
        const float* wr = Wih + row * 64 + half * 32;
        const float* hh = hm + half * 32;
        float acc = 0.f;
#pragma unroll
        for (int k4 = 0; k4 < 8; k4++) {
            float4 w4 = *(const float4*)(wr + 4 * k4);
            acc = fmaf(w4.x, hh[4 * k4 + 0], acc);
            acc = fmaf(w4.y, hh[4 * k4 + 1], acc);
            acc = fmaf(w4.z, hh[4 * k4 + 2], acc);
            acc = fmaf(w4.w, hh[4 * k4 + 3], acc);
        }
        acc += __shfl_xor(acc, 1);
        if (half == 0) gbuf[row] = acc + bih[row];
    }
    __syncthreads();

    if (tid < 32) {
        const int s = tid;
        float r = sigmoidf_(gbuf[s] + bhh[s]);
        float z = sigmoidf_(gbuf[32 + s] + bhh[32 + s]);
        float n = tanhf(gbuf[64 + s] + r * bhh[64 + s]);
        float hn_ = (1.0f - z) * n;
        hnb[s] = hn_;
        h[j * 32 + s] = hn_;
    }
    __syncthreads();

    if (tid < 64) {
        const int s = tid & 31;
        const bool isV = tid >= 32;
        const float bj = b[j];
        const float* wr = W1 + s * 67 + (isV ? 32 : 0);
        float acc = isV ? fmaf(bj, W1[s * 67 + 66], b1[s]) : bj * W1[s * 67 + 65];
#pragma unroll
        for (int k = 0; k < 32; k++) acc = fmaf(wr[k], hnb[k], acc);
        if (isV) v[j * 32 + s] = acc;
        else     uo[j * 32 + s] = acc;
    }

    if (do_out) {
        __syncthreads();
        if (tid < 32) {
            float a = rb1[tid];
            const float* rr = R1 + tid * 32;
#pragma unroll 8
            for (int k = 0; k < 32; k++) a = fmaf(rr[k], hnb[k], a);
            gbuf[tid] = fmaxf(a, 0.f);
        }
        __syncthreads();
        if (tid < 32) {
            float a = rb2[tid];
            const float* rr = R2 + tid * 32;
#pragma unroll 8
            for (int k = 0; k < 32; k++) a = fmaf(rr[k], gbuf[k], a);
            tb[tid] = fmaxf(a, 0.f);
        }
        __syncthreads();
        if (tid < 2) {
            float a = rb3[tid];
            const float* rr = R3 + tid * 32;
#pragma unroll 8
            for (int k = 0; k < 32; k++) a = fmaf(rr[k], tb[k], a);
            out[j * 2 + tid] = sigmoidf_(fmaxf(a, 0.f));
        }
    }
}

// ---------------------------------------------------------------------------
extern "C" void kernel_launch(void* const* d_in, const int* in_sizes, int n_in,
                              void* d_out, int out_size, void* d_ws, size_t ws_size,
                              hipStream_t stream)
{
    const float* J   = (const float*)d_in[0];
    const float* b   = (const float*)d_in[1];
    const float* W1  = (const float*)d_in[2];
    const float* b1  = (const float*)d_in[3];
    const float* W2  = (const float*)d_in[4];
    const float* b2  = (const float*)d_in[5];
    const float* W3  = (const float*)d_in[6];
    const float* b3  = (const float*)d_in[7];
    const float* Wih = (const float*)d_in[8];
    const float* bih = (const float*)d_in[9];
    const float* bhh = (const float*)d_in[10];
    const float* R1  = (const float*)d_in[11];
    const float* rb1 = (const float*)d_in[12];
    const float* R2  = (const float*)d_in[13];
    const float* rb2 = (const float*)d_in[14];
    const float* R3  = (const float*)d_in[15];
    const float* rb3 = (const float*)d_in[16];

    float* out = (float*)d_out;
    float* ws  = (float*)d_ws;
    float* h   = ws;
    float* v   = ws + 32768;
    float* u0  = ws + 65536;
    float* u1  = ws + 98304;
    float* Jt  = ws + 131072;
    float* cfg = ws + 131072 + NN * NN;

    k_pre<<<1153, 256, 0, stream>>>(J, b, W1, b1, W2, b2, W3, b3,
                                    Jt, h, u0, v, cfg);
    for (int s = 0; s < 5; s++) {
        const float* ui = (s & 1) ? u1 : u0;
        float*       uo = (s & 1) ? u0 : u1;
        k_step<<<1024, 256, 0, stream>>>(Jt, cfg, Wih, bih, bhh, b, b1, W1,
                                         R1, rb1, R2, rb2, R3, rb3,
                                         h, v, ui, uo, out, (s == 4) ? 1 : 0);
    }
}

// Round 12
// 199.886 us; speedup vs baseline: 1.1478x; 1.0105x over previous
//
#include <hip/hip_runtime.h>
#include <math.h>

#define NN 1024

typedef __attribute__((ext_vector_type(8))) short bf16x8;
typedef __attribute__((ext_vector_type(4))) short bf16x4;
typedef __attribute__((ext_vector_type(4))) float f32x4;
typedef __attribute__((ext_vector_type(2))) float f32x2;
typedef __attribute__((ext_vector_type(4))) unsigned int u32x4;

#if __has_builtin(__builtin_amdgcn_mfma_f32_16x16x16bf16_1k)
#define HAVE_MFMA16 1
#define MFMA16(a, b, c) __builtin_amdgcn_mfma_f32_16x16x16bf16_1k((a), (b), (c), 0, 0, 0)
#else
#define HAVE_MFMA16 0
#endif

__device__ __forceinline__ float sigmoidf_(float x) { return 1.0f / (1.0f + __expf(-x)); }

__device__ __forceinline__ unsigned int pk2(float a, float b) {
    return __builtin_amdgcn_perm(__float_as_uint(a) + 0x8000u,
                                 __float_as_uint(b) + 0x8000u, 0x03020706u);
}
__device__ __forceinline__ unsigned int pkcvt(float a, float b) {
#if __has_builtin(__builtin_amdgcn_cvt_pk_bf16_f32)
    return __builtin_bit_cast(unsigned int, __builtin_amdgcn_cvt_pk_bf16_f32(a, b));
#else
    return pk2(a, b);
#endif
}
__device__ __forceinline__ unsigned short f2bf_rne(float a) {
    unsigned int ua = __float_as_uint(a);
    ua += 0x7fffu + ((ua >> 16) & 1u);
    return (unsigned short)(ua >> 16);
}
__device__ __forceinline__ unsigned int pk2b(float a, float b) {
    return (unsigned int)f2bf_rne(a) | ((unsigned int)f2bf_rne(b) << 16);
}

// cfg layout (dwords):
//  0    w2a0 | 256 w2a1 | 512 w3a0 | 768 w3a1          (A-frags, 16x16x32)
//  1024 b2v0 | 1280 b2v1 | 1536 b3v0 | 1792 b3v1       (C-layout biases)
//  2048 wj lo | 2304 wj hi
//  2560 w3T frags g-half0: {B0a0,B0a1,B1a0,B1a1}       (16x16x16 B-frags)
//  2816 w3T frags g-half1: {B0b0,B0b1,B1b0,B1b1}
//  3072 b3 replicated lo | 3328 b3 replicated hi
#define CFG_FLOATS 3584

// ---------------------------------------------------------------------------
// k_pre: blocks 0..1023 transpose J -> Jt; 1024..1151 init h,u0,v;
//        block 1152 precomputes per-lane MFMA context into cfg.
// ---------------------------------------------------------------------------
__global__ __launch_bounds__(256) void k_pre(
    const float* __restrict__ J, const float* __restrict__ b,
    const float* __restrict__ W1, const float* __restrict__ b1,
    const float* __restrict__ W2, const float* __restrict__ b2,
    const float* __restrict__ W3, const float* __restrict__ b3,
    float* __restrict__ Jt, float* __restrict__ h,
    float* __restrict__ u0, float* __restrict__ v, float* __restrict__ cfg)
{
    __shared__ float tile[32][33];
    const int t = blockIdx.x;
    const int tid = threadIdx.x;
    if (t < 1024) {
        int tx = (t & 31) * 32, ty = (t >> 5) * 32;
        int x = tid & 31, y = tid >> 5;
#pragma unroll
        for (int r = 0; r < 4; r++)
            tile[y + 8 * r][x] = J[(size_t)(ty + y + 8 * r) * NN + tx + x];
        __syncthreads();
#pragma unroll
        for (int r = 0; r < 4; r++)
            Jt[(size_t)(tx + y + 8 * r) * NN + ty + x] = tile[x][y + 8 * r];
    } else if (t < 1152) {
        int idx = (t - 1024) * 256 + tid;
        int row = idx >> 5, mm = idx & 31;
        float bi = b[row];
        h[idx]  = 0.f;
        u0[idx] = bi * W1[mm * 67 + 65];
        v[idx]  = fmaf(bi, W1[mm * 67 + 66], b1[mm]);
    } else if (tid < 64) {
        const int l = tid, p = l & 15, q = l >> 4;
        union FU { unsigned int d[4]; unsigned short s[8]; } t0, t1, t2, t3;
        float wj[8];
#pragma unroll
        for (int jj = 0; jj < 8; jj++) {
            int k = q * 8 + jj;
            t0.s[jj] = f2bf_rne(W2[p * 32 + k]);
            t1.s[jj] = f2bf_rne(W2[(16 + p) * 32 + k]);
            t2.s[jj] = f2bf_rne(W3[p * 32 + k]);
            t3.s[jj] = f2bf_rne(W3[(16 + p) * 32 + k]);
            wj[jj] = W1[k * 67 + 64];
        }
        u32x4* cw = (u32x4*)cfg;
        cw[l]       = *(u32x4*)t0.d;
        cw[64 + l]  = *(u32x4*)t1.d;
        cw[128 + l] = *(u32x4*)t2.d;
        cw[192 + l] = *(u32x4*)t3.d;
        f32x4* cf = (f32x4*)(cfg + 1024);
        f32x4 v0, v1, v2, v3;
#pragma unroll
        for (int r = 0; r < 4; r++) {
            v0[r] = b2[q * 4 + r];  v1[r] = b2[16 + q * 4 + r];
            v2[r] = b3[q * 4 + r];  v3[r] = b3[16 + q * 4 + r];
        }
        cf[l] = v0; cf[64 + l] = v1; cf[128 + l] = v2; cf[192 + l] = v3;
        f32x4* cj = (f32x4*)(cfg + 2048);
        f32x4 wlo, whi;
#pragma unroll
        for (int r = 0; r < 4; r++) { wlo[r] = wj[r]; whi[r] = wj[4 + r]; }
        cj[l] = wlo; cj[64 + l] = whi;

        // --- new: W3^T B-frags for 16x16x16 GEMM3 (lane: n=l&15=g, k=4q+j) ---
        const int g = p;
        u32x4 fa, fb;
        fa[0] = pk2b(W3[g * 32 + 4 * q + 0],      W3[g * 32 + 4 * q + 1]);
        fa[1] = pk2b(W3[g * 32 + 4 * q + 2],      W3[g * 32 + 4 * q + 3]);
        fa[2] = pk2b(W3[g * 32 + 16 + 4 * q + 0], W3[g * 32 + 16 + 4 * q + 1]);
        fa[3] = pk2b(W3[g * 32 + 16 + 4 * q + 2], W3[g * 32 + 16 + 4 * q + 3]);
        fb[0] = pk2b(W3[(16 + g) * 32 + 4 * q + 0],      W3[(16 + g) * 32 + 4 * q + 1]);
        fb[1] = pk2b(W3[(16 + g) * 32 + 4 * q + 2],      W3[(16 + g) * 32 + 4 * q + 3]);
        fb[2] = pk2b(W3[(16 + g) * 32 + 16 + 4 * q + 0], W3[(16 + g) * 32 + 16 + 4 * q + 1]);
        fb[3] = pk2b(W3[(16 + g) * 32 + 16 + 4 * q + 2], W3[(16 + g) * 32 + 16 + 4 * q + 3]);
        u32x4* cw2 = (u32x4*)(cfg + 2560);
        cw2[l] = fa; cw2[64 + l] = fb;
        f32x4* cb3 = (f32x4*)(cfg + 3072);
        f32x4 r0, r1;
#pragma unroll
        for (int r = 0; r < 4; r++) { r0[r] = b3[g]; r1[r] = b3[16 + g]; }
        cb3[l] = r0; cb3[64 + l] = r1;
    }
}

// ---------------------------------------------------------------------------
// k_step: one recurrence step, tail fused. 1024 blocks x 256 threads,
// 4 waves x 16 tiles (8 pairs), depth-2 pair prefetch.
// GEMM3 consumes GEMM2's C-layout directly via 4 chained 16x16x16 MFMAs
// (register dataflow, no LDS-pipe relayout).  Fallback: bpermute path.
// ---------------------------------------------------------------------------
__global__ __launch_bounds__(256, 4) void k_step(
    const float* __restrict__ Jt, const float* __restrict__ cfg,
    const float* __restrict__ Wih, const float* __restrict__ bih,
    const float* __restrict__ bhh, const float* __restrict__ b,
    const float* __restrict__ b1, const float* __restrict__ W1,
    const float* __restrict__ R1, const float* __restrict__ rb1,
    const float* __restrict__ R2, const float* __restrict__ rb2,
    const float* __restrict__ R3, const float* __restrict__ rb3,
    float* __restrict__ h, float* __restrict__ v,
    const float* __restrict__ ui, float* __restrict__ uo,
    float* __restrict__ out, int do_out)
{
    __shared__ float red[4 * 32];
    __shared__ float hm[64], gbuf[96], hnb[32], tb[32];

    const int tid = threadIdx.x;
    const int w = tid >> 6;
    const int l = tid & 63;
    const int p = l & 15;
    const int q = l >> 4;
    const int j = blockIdx.x;

    // ---- coalesced per-lane context ----
    union FU { bf16x8 v; u32x4 u4; } w2a0, w2a1;
    const u32x4* cw = (const u32x4*)cfg;
    w2a0.u4 = cw[l]; w2a1.u4 = cw[64 + l];
    const f32x4* cf = (const f32x4*)(cfg + 1024);
    const f32x4 b2v0 = cf[l], b2v1 = cf[64 + l];
    const f32x4* cj = (const f32x4*)(cfg + 2048);
    const f32x4 wlo = cj[l], whi = cj[64 + l];
    f32x2 wj2[4] = { {wlo[0], wlo[1]}, {wlo[2], wlo[3]}, {whi[0], whi[1]}, {whi[2], whi[3]} };

#if HAVE_MFMA16
    union B4 { bf16x4 v; unsigned int d[2]; } B0a, B1a, B0b, B1b;
    {
        const u32x4* cw2 = (const u32x4*)(cfg + 2560);
        u32x4 fa = cw2[l], fb = cw2[64 + l];
        B0a.d[0] = fa[0]; B0a.d[1] = fa[1]; B1a.d[0] = fa[2]; B1a.d[1] = fa[3];
        B0b.d[0] = fb[0]; B0b.d[1] = fb[1]; B1b.d[0] = fb[2]; B1b.d[1] = fb[3];
    }
    const f32x4* cb3 = (const f32x4*)(cfg + 3072);
    const f32x4 b3lo = cb3[l], b3hi = cb3[64 + l];
#else
    union FU w3a0, w3a1;
    w3a0.u4 = cw[128 + l]; w3a1.u4 = cw[192 + l];
    const f32x4 b3v0 = cf[128 + l], b3v1 = cf[192 + l];
    const int s0 = (p | ((l & 16) << 1)) << 2;
    const int s1 = s0 + 64;
    const bool qlo = (l & 32) == 0;
#endif

    f32x2 vv2[4];
    {
        float4 va = *(const float4*)(v + j * 32 + q * 8);
        float4 vb = *(const float4*)(v + j * 32 + q * 8 + 4);
        vv2[0] = f32x2{va.x, va.y}; vv2[1] = f32x2{va.z, va.w};
        vv2[2] = f32x2{vb.x, vb.y}; vv2[3] = f32x2{vb.z, vb.w};
    }

    f32x4 acc0 = {0.f, 0.f, 0.f, 0.f}, acc1 = {0.f, 0.f, 0.f, 0.f};

    // ---- depth-2 pair prefetch (4 tiles in flight) ----
    const int ibase = w * 256;
    const float* jp = Jt + (size_t)j * NN + ibase + p;
    const float* up = ui + (size_t)(ibase + p) * 32 + q * 8;

    float  jw0[2], jw1[2];
    float4 ua0[2], ub0[2], ua1[2], ub1[2];
#pragma unroll
    for (int s = 0; s < 2; s++) {
        jw0[s] = jp[s * 32];       jw1[s] = jp[s * 32 + 16];
        ua0[s] = *(const float4*)(up + (size_t)s * 1024);
        ub0[s] = *(const float4*)(up + (size_t)s * 1024 + 4);
        ua1[s] = *(const float4*)(up + (size_t)s * 1024 + 512);
        ub1[s] = *(const float4*)(up + (size_t)s * 1024 + 516);
    }

#pragma unroll
    for (int tt = 0; tt < 8; ++tt) {
        const int sl = tt & 1;
        const float  jwA_c = jw0[sl], jwB_c = jw1[sl];
        const float4 uaA_c = ua0[sl], ubA_c = ub0[sl];
        const float4 uaB_c = ua1[sl], ubB_c = ub1[sl];
        if (tt < 6) {
            const float* jn = jp + (tt + 2) * 32;
            const float* un = up + (size_t)(tt + 2) * 1024;
            jw0[sl] = jn[0];  jw1[sl] = jn[16];
            ua0[sl] = *(const float4*)(un);
            ub0[sl] = *(const float4*)(un + 4);
            ua1[sl] = *(const float4*)(un + 512);
            ub1[sl] = *(const float4*)(un + 516);
        }

#pragma unroll
        for (int half = 0; half < 2; ++half) {
            const float  jw = half ? jwB_c : jwA_c;
            const float4 ua_c = half ? uaB_c : uaA_c;
            const float4 ub_c = half ? ubB_c : ubA_c;

            const f32x2 jw2 = {jw, jw};
            const f32x2 z2 = {0.f, 0.f};
            const f32x4 z4 = {0.f, 0.f, 0.f, 0.f};

            f32x2 x0 = {ua_c.x, ua_c.y}, x1 = {ua_c.z, ua_c.w};
            f32x2 x2 = {ub_c.x, ub_c.y}, x3 = {ub_c.z, ub_c.w};
            x0 = jw2 * wj2[0] + (x0 + vv2[0]);
            x1 = jw2 * wj2[1] + (x1 + vv2[1]);
            x2 = jw2 * wj2[2] + (x2 + vv2[2]);
            x3 = jw2 * wj2[3] + (x3 + vv2[3]);
            x0 = __builtin_elementwise_max(x0, z2);
            x1 = __builtin_elementwise_max(x1, z2);
            x2 = __builtin_elementwise_max(x2, z2);
            x3 = __builtin_elementwise_max(x3, z2);

            union BU { u32x4 u4; bf16x8 v; unsigned int d[4]; } bx;
            bx.d[0] = pkcvt(x0[0], x0[1]);
            bx.d[1] = pkcvt(x1[0], x1[1]);
            bx.d[2] = pkcvt(x2[0], x2[1]);
            bx.d[3] = pkcvt(x3[0], x3[1]);

            f32x4 c0 = __builtin_amdgcn_mfma_f32_16x16x32_bf16(w2a0.v, bx.v, b2v0, 0, 0, 0);
            f32x4 c1 = __builtin_amdgcn_mfma_f32_16x16x32_bf16(w2a1.v, bx.v, b2v1, 0, 0, 0);
            c0 = __builtin_elementwise_max(c0, z4);
            c1 = __builtin_elementwise_max(c1, z4);

#if HAVE_MFMA16
            // Z (= Y^T) is already in A-operand layout of 16x16x16.
            union B4 { bf16x4 v; unsigned int d[2]; } A0, A1;
            A0.d[0] = pkcvt(c0[0], c0[1]); A0.d[1] = pkcvt(c0[2], c0[3]);
            A1.d[0] = pkcvt(c1[0], c1[1]); A1.d[1] = pkcvt(c1[2], c1[3]);

            f32x4 e0 = MFMA16(A0.v, B0a.v, b3lo);
            e0 = MFMA16(A1.v, B1a.v, e0);
            f32x4 e1 = MFMA16(A0.v, B0b.v, b3hi);
            e1 = MFMA16(A1.v, B1b.v, e1);
            acc0 = acc0 + __builtin_elementwise_max(e0, z4);
            acc1 = acc1 + __builtin_elementwise_max(e1, z4);
#else
            const int d0 = (int)pkcvt(c0[0], c0[1]);
            const int d1 = (int)pkcvt(c0[2], c0[3]);
            const int d2 = (int)pkcvt(c1[0], c1[1]);
            const int d3 = (int)pkcvt(c1[2], c1[3]);
            const int A0_ = __builtin_amdgcn_ds_bpermute(s0, d0);
            const int A1_ = __builtin_amdgcn_ds_bpermute(s0, d1);
            const int A2_ = __builtin_amdgcn_ds_bpermute(s1, d0);
            const int A3_ = __builtin_amdgcn_ds_bpermute(s1, d1);
            const int B0_ = __builtin_amdgcn_ds_bpermute(s0, d2);
            const int B1_ = __builtin_amdgcn_ds_bpermute(s0, d3);
            const int B2_ = __builtin_amdgcn_ds_bpermute(s1, d2);
            const int B3_ = __builtin_amdgcn_ds_bpermute(s1, d3);
            union BU yr;
            yr.d[0] = (unsigned)(qlo ? A0_ : B0_);
            yr.d[1] = (unsigned)(qlo ? A1_ : B1_);
            yr.d[2] = (unsigned)(qlo ? A2_ : B2_);
            yr.d[3] = (unsigned)(qlo ? A3_ : B3_);
            f32x4 e0 = __builtin_amdgcn_mfma_f32_16x16x32_bf16(w3a0.v, yr.v, b3v0, 0, 0, 0);
            f32x4 e1 = __builtin_amdgcn_mfma_f32_16x16x32_bf16(w3a1.v, yr.v, b3v1, 0, 0, 0);
            acc0 = acc0 + __builtin_elementwise_max(e0, z4);
            acc1 = acc1 + __builtin_elementwise_max(e1, z4);
#endif
        }
    }

#if HAVE_MFMA16
    // acc lane layout: col g = l&15 (acc0: g, acc1: 16+g), rows p = 4q+r.
    float s0v = acc0[0] + acc0[1] + acc0[2] + acc0[3];
    float s1v = acc1[0] + acc1[1] + acc1[2] + acc1[3];
    s0v += __shfl_xor(s0v, 16);  s0v += __shfl_xor(s0v, 32);
    s1v += __shfl_xor(s1v, 16);  s1v += __shfl_xor(s1v, 32);
    if (l < 16) { red[w * 32 + l] = s0v;  red[w * 32 + 16 + l] = s1v; }
#else
#pragma unroll
    for (int bit = 1; bit < 16; bit <<= 1) {
#pragma unroll
        for (int r = 0; r < 4; r++) {
            acc0[r] += __shfl_xor(acc0[r], bit);
            acc1[r] += __shfl_xor(acc1[r], bit);
        }
    }
    if (p == 0) {
#pragma unroll
        for (int r = 0; r < 4; r++) {
            red[w * 32 + q * 4 + r]      = acc0[r];
            red[w * 32 + 16 + q * 4 + r] = acc1[r];
        }
    }
#endif
    __syncthreads();

    // ---- tail: GRU + u/v refresh (+ readout) ----
    if (tid < 64) {
        float val;
        if (tid < 32) val = h[j * 32 + tid];
        else {
            int s = tid - 32;
            val = red[s] + red[32 + s] + red[64 + s] + red[96 + s];
        }
        hm[tid] = val;
    }
    __syncthreads();

    if (tid < 192) {
        const int row = tid >> 1, half = tid & 1;
        const float* wr = Wih + row * 64 + half * 32;
        const float* hh = hm + half * 32;
        float acc = 0.f;
#pragma unroll
        for (int k4 = 0; k4 < 8; k4++) {
            float4 w4 = *(const float4*)(wr + 4 * k4);
            acc = fmaf(w4.x, hh[4 * k4 + 0], acc);
            acc = fmaf(w4.y, hh[4 * k4 + 1], acc);
            acc = fmaf(w4.z, hh[4 * k4 + 2], acc);
            acc = fmaf(w4.w, hh[4 * k4 + 3], acc);
        }
        acc += __shfl_xor(acc, 1);
        if (half == 0) gbuf[row] = acc + bih[row];
    }
    __syncthreads();

    if (tid < 32) {
        const int s = tid;
        float r = sigmoidf_(gbuf[s] + bhh[s]);
        float z = sigmoidf_(gbuf[32 + s] + bhh[32 + s]);
        float n = tanhf(gbuf[64 + s] + r * bhh[64 + s]);
        float hn_ = (1.0f - z) * n;
        hnb[s] = hn_;
        h[j * 32 + s] = hn_;
    }
    __syncthreads();

    if (tid < 64) {
        const int s = tid & 31;
        const bool isV = tid >= 32;
        const float bj = b[j];
        const float* wr = W1 + s * 67 + (isV ? 32 : 0);
        float acc = isV ? fmaf(bj, W1[s * 67 + 66], b1[s]) : bj * W1[s * 67 + 65];
#pragma unroll
        for (int k = 0; k < 32; k++) acc = fmaf(wr[k], hnb[k], acc);
        if (isV) v[j * 32 + s] = acc;
        else     uo[j * 32 + s] = acc;
    }

    if (do_out) {
        __syncthreads();
        if (tid < 32) {
            float a = rb1[tid];
            const float* rr = R1 + tid * 32;
#pragma unroll 8
            for (int k = 0; k < 32; k++) a = fmaf(rr[k], hnb[k], a);
            gbuf[tid] = fmaxf(a, 0.f);
        }
        __syncthreads();
        if (tid < 32) {
            float a = rb2[tid];
            const float* rr = R2 + tid * 32;
#pragma unroll 8
            for (int k = 0; k < 32; k++) a = fmaf(rr[k], gbuf[k], a);
            tb[tid] = fmaxf(a, 0.f);
        }
        __syncthreads();
        if (tid < 2) {
            float a = rb3[tid];
            const float* rr = R3 + tid * 32;
#pragma unroll 8
            for (int k = 0; k < 32; k++) a = fmaf(rr[k], tb[k], a);
            out[j * 2 + tid] = sigmoidf_(fmaxf(a, 0.f));
        }
    }
}

// ---------------------------------------------------------------------------
extern "C" void kernel_launch(void* const* d_in, const int* in_sizes, int n_in,
                              void* d_out, int out_size, void* d_ws, size_t ws_size,
                              hipStream_t stream)
{
    const float* J   = (const float*)d_in[0];
    const float* b   = (const float*)d_in[1];
    const float* W1  = (const float*)d_in[2];
    const float* b1  = (const float*)d_in[3];
    const float* W2  = (const float*)d_in[4];
    const float* b2  = (const float*)d_in[5];
    const float* W3  = (const float*)d_in[6];
    const float* b3  = (const float*)d_in[7];
    const float* Wih = (const float*)d_in[8];
    const float* bih = (const float*)d_in[9];
    const float* bhh = (const float*)d_in[10];
    const float* R1  = (const float*)d_in[11];
    const float* rb1 = (const float*)d_in[12];
    const float* R2  = (const float*)d_in[13];
    const float* rb2 = (const float*)d_in[14];
    const float* R3  = (const float*)d_in[15];
    const float* rb3 = (const float*)d_in[16];

    float* out = (float*)d_out;
    float* ws  = (float*)d_ws;
    float* h   = ws;
    float* v   = ws + 32768;
    float* u0  = ws + 65536;
    float* u1  = ws + 98304;
    float* Jt  = ws + 131072;
    float* cfg = ws + 131072 + NN * NN;

    k_pre<<<1153, 256, 0, stream>>>(J, b, W1, b1, W2, b2, W3, b3,
                                    Jt, h, u0, v, cfg);
    for (int s = 0; s < 5; s++) {
        const float* ui = (s & 1) ? u1 : u0;
        float*       uo = (s & 1) ? u0 : u1;
        k_step<<<1024, 256, 0, stream>>>(Jt, cfg, Wih, bih, bhh, b, b1, W1,
                                         R1, rb1, R2, rb2, R3, rb3,
                                         h, v, ui, uo, out, (s == 4) ? 1 : 0);
    }
}